// Round 1
// baseline (182.201 us; speedup 1.0000x reference)
//
#include <hip/hip_runtime.h>
#include <hip/hip_bf16.h>

// Problem constants (from reference): M=3 models, B=16 images, N=512 boxes,
// K = M*N = 1536 boxes/image, 12 classes, IOU_THR=0.5.
// Output: (B, K, 5) float32 = sorted (x1,y1,x2,y2,score) * keep.
#define MM 3
#define BB 16
#define NN 512
#define KK 1536          // = MM*NN, and exactly 24*64
#define KPAD 2048        // bitonic pad
#define NW 24            // 64-bit words per row bitmask (1536/64)

// ---------------- Kernel A: gather + stable descending sort ----------------
// key = (~bits(score) << 32) | origIdx  -> ascending u64 sort == descending
// score, ties broken by ascending original index (matches jnp.argsort(-s)).
// Scores are >= 0 so bit pattern order == value order. Score is recovered
// bit-exactly from the key high word.
__global__ __launch_bounds__(256) void prep_kernel(
    const float* __restrict__ boxes, const float* __restrict__ scores,
    const int* __restrict__ labels, const float* __restrict__ weights,
    float* __restrict__ sboxes, float* __restrict__ sscores,
    int* __restrict__ slabels, float* __restrict__ sarea) {
  int b = blockIdx.x, tid = threadIdx.x;
  __shared__ unsigned long long key[KPAD];
  float w0 = weights[0], w1 = weights[1], w2 = weights[2];
  for (int i = tid; i < KPAD; i += 256) {
    unsigned long long kv = 0xFFFFFFFFFFFFFFFFULL;  // pad sorts last
    if (i < KK) {
      int m = i >> 9, n = i & 511;
      float wm = (m == 0) ? w0 : ((m == 1) ? w1 : w2);
      float s = scores[(m * BB + b) * NN + n] * wm;
      kv = ((unsigned long long)(~__float_as_uint(s)) << 32) | (unsigned)i;
    }
    key[i] = kv;
  }
  __syncthreads();
  // bitonic sort, ascending
  for (int k = 2; k <= KPAD; k <<= 1) {
    for (int j = k >> 1; j > 0; j >>= 1) {
      for (int t = tid; t < (KPAD >> 1); t += 256) {
        int i = ((t & ~(j - 1)) << 1) | (t & (j - 1));
        int p = i + j;
        unsigned long long a = key[i], c = key[p];
        bool asc = (i & k) == 0;
        if ((a > c) == asc) { key[i] = c; key[p] = a; }
      }
      __syncthreads();
    }
  }
  for (int i = tid; i < KK; i += 256) {
    unsigned long long kv = key[i];
    int o = (int)(kv & 0xFFFFFFFFu);
    float s = __uint_as_float(~(unsigned)(kv >> 32));
    int m = o >> 9, n = o & 511;
    const float* bp = boxes + (size_t)((m * BB + b) * NN + n) * 4;
    float x1 = bp[0], y1 = bp[1], x2 = bp[2], y2 = bp[3];
    ((float4*)sboxes)[b * KK + i] = make_float4(x1, y1, x2, y2);
    sscores[b * KK + i] = s;
    slabels[b * KK + i] = labels[(m * BB + b) * NN + n];
    sarea[b * KK + i] = (x2 - x1) * (y2 - y1);
  }
}

// ---------------- Kernel B: suppression bitmask matrix ----------------
// grid (24, 16): blockIdx.x = 64-row tile, blockIdx.y = image.
// thread = (row r in tile, column chunk of 384). Row i's mask has bits only
// for j < i: suppress = (iou > 0.5) && (label_j == label_i).
__global__ __launch_bounds__(256) void matrix_kernel(
    const float* __restrict__ sboxes, const int* __restrict__ slabels,
    const float* __restrict__ sarea, unsigned long long* __restrict__ mat,
    unsigned* __restrict__ flags) {
#pragma clang fp contract(off)
  int b = blockIdx.y, tile = blockIdx.x, tid = threadIdx.x;
  __shared__ float4 lb[KK];
  __shared__ int ll[KK];
  __shared__ float la[KK];
  __shared__ int rflag[64][4];
  const float4* sb4 = (const float4*)sboxes;
  for (int i = tid; i < KK; i += 256) {
    lb[i] = sb4[b * KK + i];
    ll[i] = slabels[b * KK + i];
    la[i] = sarea[b * KK + i];
  }
  __syncthreads();
  int r = tid & 63, chunk = tid >> 6;
  int row = tile * 64 + r;
  float4 bi = lb[row];
  int li = ll[row];
  float ai = la[row];
  int any = 0;
  int cbase = chunk * 384;
  for (int wI = 0; wI < 6; ++wI) {
    unsigned long long bits = 0;
    int base = cbase + wI * 64;
    if (base < row) {
      int jmax = row - base; if (jmax > 64) jmax = 64;
      for (int jj = 0; jj < jmax; ++jj) {
        int j = base + jj;
        float4 bj = lb[j];
        float iw = fminf(bi.z, bj.z) - fmaxf(bi.x, bj.x); iw = fmaxf(iw, 0.0f);
        float ih = fminf(bi.w, bj.w) - fmaxf(bi.y, bj.y); ih = fmaxf(ih, 0.0f);
        float inter = iw * ih;
        float uni = ai + la[j] - inter;
        float iou = inter / fmaxf(uni, 1e-9f);   // match reference: real divide
        if (iou > 0.5f && ll[j] == li) bits |= (1ULL << jj);
      }
    }
    mat[(size_t)(b * KK + row) * NW + chunk * 6 + wI] = bits;
    any |= (bits != 0ULL);
  }
  rflag[r][chunk] = any;
  __syncthreads();
  if (chunk == 0)
    flags[b * KK + row] = rflag[r][0] | rflag[r][1] | rflag[r][2] | rflag[r][3];
}

// ---------------- Kernel C: sparse sequential scan + output ----------------
// One wave per image does the greedy scan. Rows with no suppressors (almost
// all of them, with random boxes) are kept 64-at-a-time via a ballot over the
// flags; only flagged rows do the 24-word mask AND against the keep bitmask.
__global__ __launch_bounds__(256) void scan_kernel(
    const float* __restrict__ sboxes, const float* __restrict__ sscores,
    const unsigned long long* __restrict__ mat,
    const unsigned* __restrict__ flags, float* __restrict__ out) {
  int b = blockIdx.x, tid = threadIdx.x;
  __shared__ unsigned long long keepLDS[NW];
  if (tid < 64) {
    int lane = tid;
    unsigned long long kw = 0;  // lane l holds keep word l (l < 24)
    for (int wb = 0; wb < NW; ++wb) {
      unsigned f = flags[b * KK + wb * 64 + lane];
      unsigned long long interesting = __ballot(f != 0);
      if (lane == wb) kw |= ~interesting;  // flag-free rows: kept immediately
      while (interesting) {
        int rr = __ffsll(interesting) - 1;
        interesting &= interesting - 1;
        int i = wb * 64 + rr;
        unsigned long long rw =
            (lane < NW) ? mat[(size_t)(b * KK + i) * NW + lane] : 0ULL;
        unsigned long long conf = __ballot((rw & kw) != 0ULL);
        if (conf == 0ULL && lane == wb) kw |= (1ULL << rr);
      }
    }
    if (lane < NW) keepLDS[lane] = kw;
  }
  __syncthreads();
  for (int e = tid; e < KK * 5; e += 256) {
    int row = e / 5, c = e - row * 5;
    bool k = (keepLDS[row >> 6] >> (row & 63)) & 1ULL;
    float v = 0.0f;
    if (k) v = (c < 4) ? sboxes[(size_t)(b * KK + row) * 4 + c]
                       : sscores[b * KK + row];
    out[(size_t)b * (KK * 5) + e] = v;
  }
}

extern "C" void kernel_launch(void* const* d_in, const int* in_sizes, int n_in,
                              void* d_out, int out_size, void* d_ws, size_t ws_size,
                              hipStream_t stream) {
  (void)in_sizes; (void)n_in; (void)out_size;
  const float* boxes   = (const float*)d_in[0];  // (M,B,N,4)
  const float* scores  = (const float*)d_in[1];  // (M,B,N)
  const int*   labels  = (const int*)d_in[2];    // (M,B,N)
  const float* weights = (const float*)d_in[3];  // (M,)
  float* out = (float*)d_out;                    // (B,K,5)

  // ws layout (bytes), total ~5.3 MB
  char* base = (char*)d_ws;
  float* sboxes  = (float*)(base + 0);                       // B*K*4 f32  = 393216 B
  float* sscores = (float*)(base + 393216);                  // B*K f32    =  98304 B
  int*   slabels = (int*)  (base + 491520);                  // B*K i32    =  98304 B
  float* sarea   = (float*)(base + 589824);                  // B*K f32    =  98304 B
  unsigned* flags = (unsigned*)(base + 688128);              // B*K u32    =  98304 B
  unsigned long long* mat = (unsigned long long*)(base + 786432); // B*K*24 u64 = 4718592 B
  (void)ws_size;  // needs ~5.51 MB

  prep_kernel<<<BB, 256, 0, stream>>>(boxes, scores, labels, weights,
                                      sboxes, sscores, slabels, sarea);
  matrix_kernel<<<dim3(KK / 64, BB), 256, 0, stream>>>(sboxes, slabels, sarea,
                                                       mat, flags);
  scan_kernel<<<BB, 256, 0, stream>>>(sboxes, sscores, mat, flags, out);
}

// Round 2
// 129.705 us; speedup vs baseline: 1.4047x; 1.4047x over previous
//
#include <hip/hip_runtime.h>
#include <hip/hip_bf16.h>

// M=3 models, B=16 images, N=512 boxes, K=M*N=1536/image, 12 classes, IoU 0.5.
// Output (B,K,5) f32 = score-sorted (x1,y1,x2,y2,score) * keep.
#define MM 3
#define BB 16
#define NN 512
#define KK 1536          // 24*64
#define NW 24            // 64-bit mask words per row

// ---------------- Kernel A: barrier-free rank sort + scatter ----------------
// key = (~bits(score*w) << 16) | origIdx : ascending u64 == descending score,
// ties by ascending original index (matches stable argsort(-s)). Scores >= 0
// so the bit pattern is order-preserving; score recovered bit-exactly.
// rank_i = #{j : key_j < key_i}  -> direct scatter, no barriers after load.
__global__ __launch_bounds__(256) void rank_kernel(
    const float* __restrict__ boxes, const float* __restrict__ scores,
    const int* __restrict__ labels, const float* __restrict__ weights,
    float* __restrict__ sboxes, float* __restrict__ sscores,
    int* __restrict__ slabels, float* __restrict__ sarea,
    unsigned long long* __restrict__ flagw) {
  int b = blockIdx.y, tid = threadIdx.x;
  __shared__ unsigned long long kl[KK];
  float w0 = weights[0], w1 = weights[1], w2 = weights[2];
  for (int t = tid; t < KK; t += 256) {
    int m = t >> 9, n = t & 511;
    float wm = (m == 0) ? w0 : ((m == 1) ? w1 : w2);
    float s = scores[(m * BB + b) * NN + n] * wm;
    kl[t] = ((unsigned long long)(~__float_as_uint(s)) << 16) | (unsigned)t;
  }
  if (blockIdx.x == 0 && tid < NW) flagw[b * NW + tid] = 0ULL;  // zero poison
  __syncthreads();
  int i = blockIdx.x * 256 + tid;  // element this thread ranks
  unsigned long long ki = kl[i];
  int rank = 0;
  const ulonglong2* k2 = (const ulonglong2*)kl;  // broadcast LDS reads
#pragma unroll 4
  for (int j = 0; j < KK / 2; ++j) {
    ulonglong2 kk = k2[j];
    rank += (int)(kk.x < ki) + (int)(kk.y < ki);
  }
  int m = i >> 9, n = i & 511;
  float4 box = ((const float4*)boxes)[(m * BB + b) * NN + n];
  float s = __uint_as_float(~(unsigned)(ki >> 16));
  ((float4*)sboxes)[b * KK + rank] = box;
  sscores[b * KK + rank] = s;
  slabels[b * KK + rank] = labels[(m * BB + b) * NN + n];
  sarea[b * KK + rank] = (box.z - box.x) * (box.w - box.y);
}

// ---------------- Kernel B: 64x64 lower-triangular IoU tiles ----------------
// grid (300, 16): blockIdx.x enumerates tile pairs (rt,ct), ct<=rt. Wave w
// handles rows w*16..w*16+15; the 64 lanes are the 64 cols -> __ballot builds
// each mask word directly. Divide-free exact compare:
//   fl(inter/uni) > 0.5  <=>  2*inter > uni*(1+2^-24)   (exact in f64)
__global__ __launch_bounds__(256) void tile_kernel(
    const float* __restrict__ sboxes, const int* __restrict__ slabels,
    const float* __restrict__ sarea, unsigned long long* __restrict__ mat,
    unsigned long long* __restrict__ flagw) {
#pragma clang fp contract(off)
  int b = blockIdx.y, tid = threadIdx.x;
  int t = blockIdx.x;
  int rt = (int)((sqrtf(8.0f * (float)t + 1.0f) - 1.0f) * 0.5f);
  while ((rt + 1) * (rt + 2) / 2 <= t) ++rt;
  while (rt * (rt + 1) / 2 > t) --rt;
  int ct = t - rt * (rt + 1) / 2;   // 0 <= ct <= rt <= 23
  int rowbase = rt * 64, colbase = ct * 64;

  __shared__ float4 rb[64]; __shared__ float ra[64]; __shared__ int rl[64];
  __shared__ float4 cb[64]; __shared__ float ca[64]; __shared__ int cl[64];
  const float4* sb4 = (const float4*)sboxes;
  if (tid < 64) {
    rb[tid] = sb4[b * KK + rowbase + tid];
    ra[tid] = sarea[b * KK + rowbase + tid];
    rl[tid] = slabels[b * KK + rowbase + tid];
  } else if (tid < 128) {
    int u = tid - 64;
    cb[u] = sb4[b * KK + colbase + u];
    ca[u] = sarea[b * KK + colbase + u];
    cl[u] = slabels[b * KK + colbase + u];
  }
  __syncthreads();

  int lane = tid & 63, wave = tid >> 6;
  float4 bj = cb[lane]; float aj = ca[lane]; int lj = cl[lane];
  unsigned long long wflag = 0;
#pragma unroll 4
  for (int s = 0; s < 16; ++s) {
    int r = wave * 16 + s;
    float4 bi = rb[r];          // broadcast
    float ai = ra[r]; int li = rl[r];
    float iw = fminf(bi.z, bj.z) - fmaxf(bi.x, bj.x); iw = fmaxf(iw, 0.0f);
    float ih = fminf(bi.w, bj.w) - fmaxf(bi.y, bj.y); ih = fmaxf(ih, 0.0f);
    float inter = iw * ih;
    float uni = (ai + aj) - inter;                 // matches ref order, no fma
    bool sup = ((double)inter * 2.0 > (double)uni * (1.0 + 0x1p-24)) && (lj == li);
    unsigned long long bits = __ballot(sup);
    if (rt == ct) bits &= (1ULL << r) - 1ULL;      // keep only j < i
    if (lane == 0) mat[(size_t)(b * KK + rowbase + r) * NW + ct] = bits;
    if (bits) wflag |= 1ULL << r;
  }
  if (lane == 0 && wflag) atomicOr(&flagw[b * NW + rt], wflag);
}

// ---------------- Kernel C: sparse pipelined scan + output ----------------
// Wave 0 per image: unflagged rows kept immediately (mask init = ~flags);
// flagged rows (sorted list built via popc+prefix-scan) processed in order
// with 2-deep prefetch of their 24-word masks. Then all 256 threads emit.
__global__ __launch_bounds__(256) void scan_kernel(
    const float* __restrict__ sboxes, const float* __restrict__ sscores,
    const unsigned long long* __restrict__ mat,
    const unsigned long long* __restrict__ flagw, float* __restrict__ out) {
  int b = blockIdx.x, tid = threadIdx.x;
  __shared__ unsigned long long keepLDS[NW];
  __shared__ int list[KK];
  if (tid < 64) {
    int lane = tid;
    unsigned long long fwl = (lane < NW) ? flagw[b * NW + lane] : 0ULL;
    int cnt = __popcll(fwl);
    int off = cnt;                       // inclusive prefix over 64 lanes
    for (int d = 1; d < 64; d <<= 1) {
      int o = __shfl_up(off, d);
      if (lane >= d) off += o;
    }
    int excl = off - cnt;
    int F = __shfl(off, 63);
    unsigned long long w = fwl; int k = 0;
    while (w) {                          // emit this word's flagged rows
      int r = __ffsll(w) - 1; w &= w - 1;
      list[excl + k] = lane * 64 + r; ++k;
    }
    unsigned long long kw = (lane < NW) ? ~fwl : 0ULL;  // unflagged -> kept
#define LOADROW(i) ((lane <= ((i) >> 6)) \
    ? mat[(size_t)(b * KK + (i)) * NW + lane] : 0ULL)
    unsigned long long rw0 = 0, rw1 = 0;
    if (F > 0) rw0 = LOADROW(list[0]);
    if (F > 1) rw1 = LOADROW(list[1]);
    for (int q = 0; q < F; ++q) {
      unsigned long long rw2 = (q + 2 < F) ? LOADROW(list[q + 2]) : 0ULL;
      int i = list[q];
      unsigned long long conf = __ballot((rw0 & kw) != 0ULL);
      if (conf == 0ULL && lane == (i >> 6)) kw |= 1ULL << (i & 63);
      rw0 = rw1; rw1 = rw2;
    }
#undef LOADROW
    if (lane < NW) keepLDS[lane] = kw;
  }
  __syncthreads();
  for (int e = tid; e < KK * 5; e += 256) {
    int row = e / 5, c = e - row * 5;
    bool k = (keepLDS[row >> 6] >> (row & 63)) & 1ULL;
    float v = 0.0f;
    if (k) v = (c < 4) ? sboxes[(size_t)(b * KK + row) * 4 + c]
                       : sscores[b * KK + row];
    out[(size_t)b * (KK * 5) + e] = v;
  }
}

extern "C" void kernel_launch(void* const* d_in, const int* in_sizes, int n_in,
                              void* d_out, int out_size, void* d_ws, size_t ws_size,
                              hipStream_t stream) {
  (void)in_sizes; (void)n_in; (void)out_size; (void)ws_size;
  const float* boxes   = (const float*)d_in[0];  // (M,B,N,4)
  const float* scores  = (const float*)d_in[1];  // (M,B,N)
  const int*   labels  = (const int*)d_in[2];    // (M,B,N)
  const float* weights = (const float*)d_in[3];  // (M,)
  float* out = (float*)d_out;                    // (B,K,5)

  // ws layout (bytes), total ~5.16 MB
  char* base = (char*)d_ws;
  float* sboxes  = (float*)(base + 0);                   // B*K*4 f32
  float* sscores = (float*)(base + 393216);              // B*K f32
  int*   slabels = (int*)  (base + 491520);              // B*K i32
  float* sarea   = (float*)(base + 589824);              // B*K f32
  unsigned long long* flagw = (unsigned long long*)(base + 688128); // B*NW u64
  unsigned long long* mat   = (unsigned long long*)(base + 691200); // B*K*NW u64

  rank_kernel<<<dim3(KK / 256, BB), 256, 0, stream>>>(
      boxes, scores, labels, weights, sboxes, sscores, slabels, sarea, flagw);
  tile_kernel<<<dim3(NW * (NW + 1) / 2, BB), 256, 0, stream>>>(
      sboxes, slabels, sarea, mat, flagw);
  scan_kernel<<<BB, 256, 0, stream>>>(sboxes, sscores, mat, flagw, out);
}

// Round 4
// 129.054 us; speedup vs baseline: 1.4118x; 1.0051x over previous
//
#include <hip/hip_runtime.h>
#include <hip/hip_bf16.h>

// M=3 models, B=16 images, N=512 boxes, K=M*N=1536/image, 12 classes, IoU 0.5.
// Output (B,K,5) f32 = score-sorted (x1,y1,x2,y2,score) * keep.
#define MM 3
#define BB 16
#define NN 512
#define KK 1536          // 24*64
#define NW 24            // 64-bit mask words per row

// ---------------- Kernel A: barrier-free rank sort + scatter ----------------
// key = (~bits(score*w) << 16) | origIdx : ascending u64 == descending score,
// ties by ascending original index (matches stable argsort(-s)). Scores >= 0
// so the bit pattern is order-preserving; score recovered bit-exactly.
// 64 threads/block, 2 elements/thread -> 192 blocks = 1 block/CU, one wave on
// the CU's LDS port.
__global__ __launch_bounds__(64) void rank_kernel(
    const float* __restrict__ boxes, const float* __restrict__ scores,
    const int* __restrict__ labels, const float* __restrict__ weights,
    float* __restrict__ sboxes, float* __restrict__ sscores,
    int* __restrict__ slabels, float* __restrict__ sarea,
    unsigned long long* __restrict__ flagw) {
  int b = blockIdx.y, tid = threadIdx.x;
  __shared__ unsigned long long kl[KK];
  float w0 = weights[0], w1 = weights[1], w2 = weights[2];
  for (int t = tid; t < KK; t += 64) {
    int m = t >> 9, n = t & 511;
    float wm = (m == 0) ? w0 : ((m == 1) ? w1 : w2);
    float s = scores[(m * BB + b) * NN + n] * wm;
    kl[t] = ((unsigned long long)(~__float_as_uint(s)) << 16) | (unsigned)t;
  }
  if (blockIdx.x == 0 && tid < NW) flagw[b * NW + tid] = 0ULL;  // zero poison
  __syncthreads();
  int i0 = blockIdx.x * 128 + tid, i1 = i0 + 64;
  unsigned long long k0 = kl[i0], k1 = kl[i1];
  int r0 = 0, r1 = 0;
  const ulonglong2* k2 = (const ulonglong2*)kl;  // broadcast LDS reads
#pragma unroll 8
  for (int j = 0; j < KK / 2; ++j) {
    ulonglong2 kk = k2[j];
    r0 += (int)(kk.x < k0) + (int)(kk.y < k0);
    r1 += (int)(kk.x < k1) + (int)(kk.y < k1);
  }
#pragma unroll
  for (int e = 0; e < 2; ++e) {
    unsigned long long ki = e ? k1 : k0;
    int rank = e ? r1 : r0;
    int o = (int)(ki & 0xFFFFu);
    int m = o >> 9, n = o & 511;
    float4 box = ((const float4*)boxes)[(m * BB + b) * NN + n];
    ((float4*)sboxes)[b * KK + rank] = box;
    sscores[b * KK + rank] = __uint_as_float(~(unsigned)(ki >> 16));
    slabels[b * KK + rank] = labels[(m * BB + b) * NN + n];
    sarea[b * KK + rank] = (box.z - box.x) * (box.w - box.y);
  }
}

// ---------------- Kernel B: 64x64 lower-triangular IoU tiles ----------------
// grid (300, 16): blockIdx.x enumerates tile pairs (rt,ct), ct<=rt. Wave w
// handles rows w*16..w*16+15; the 64 lanes are the 64 cols -> __ballot builds
// each mask word directly. Divide-free exact compare:
//   fl(inter/uni) > 0.5  <=>  2*inter > uni*(1+2^-24)   (exact in f64)
__global__ __launch_bounds__(256) void tile_kernel(
    const float* __restrict__ sboxes, const int* __restrict__ slabels,
    const float* __restrict__ sarea, unsigned long long* __restrict__ mat,
    unsigned long long* __restrict__ flagw) {
#pragma clang fp contract(off)
  int b = blockIdx.y, tid = threadIdx.x;
  int t = blockIdx.x;
  int rt = (int)((sqrtf(8.0f * (float)t + 1.0f) - 1.0f) * 0.5f);
  while ((rt + 1) * (rt + 2) / 2 <= t) ++rt;
  while (rt * (rt + 1) / 2 > t) --rt;
  int ct = t - rt * (rt + 1) / 2;   // 0 <= ct <= rt <= 23
  int rowbase = rt * 64, colbase = ct * 64;

  __shared__ float4 rb[64]; __shared__ float ra[64]; __shared__ int rl[64];
  __shared__ float4 cb[64]; __shared__ float ca[64]; __shared__ int cl[64];
  const float4* sb4 = (const float4*)sboxes;
  if (tid < 64) {
    rb[tid] = sb4[b * KK + rowbase + tid];
    ra[tid] = sarea[b * KK + rowbase + tid];
    rl[tid] = slabels[b * KK + rowbase + tid];
  } else if (tid < 128) {
    int u = tid - 64;
    cb[u] = sb4[b * KK + colbase + u];
    ca[u] = sarea[b * KK + colbase + u];
    cl[u] = slabels[b * KK + colbase + u];
  }
  __syncthreads();

  int lane = tid & 63, wave = tid >> 6;
  float4 bj = cb[lane]; float aj = ca[lane]; int lj = cl[lane];
  unsigned long long wflag = 0;
#pragma unroll 4
  for (int s = 0; s < 16; ++s) {
    int r = wave * 16 + s;
    float4 bi = rb[r];          // broadcast
    float ai = ra[r]; int li = rl[r];
    float iw = fminf(bi.z, bj.z) - fmaxf(bi.x, bj.x); iw = fmaxf(iw, 0.0f);
    float ih = fminf(bi.w, bj.w) - fmaxf(bi.y, bj.y); ih = fmaxf(ih, 0.0f);
    float inter = iw * ih;
    float uni = (ai + aj) - inter;                 // matches ref order, no fma
    bool sup = ((double)inter * 2.0 > (double)uni * (1.0 + 0x1p-24)) && (lj == li);
    unsigned long long bits = __ballot(sup);
    if (rt == ct) bits &= (1ULL << r) - 1ULL;      // keep only j < i
    if (lane == 0) mat[(size_t)(b * KK + rowbase + r) * NW + ct] = bits;
    if (bits) wflag |= 1ULL << r;
  }
  if (lane == 0 && wflag) atomicOr(&flagw[b * NW + rt], wflag);
}

// ---------------- Kernel C: chunked-LDS sequential scan + output ----------
// Wave 0 builds the flagged-row list; unflagged rows kept immediately. Then,
// per 256-row chunk, ALL 256 threads cooperatively stage the chunk's mask
// rows into LDS (parallel L2/L3 loads), and wave 0 scans from LDS — the
// per-iteration LDS read is independent of the keep chain, so it pipelines.
// NOTE: every __shfl here runs with ALL 64 lanes of wave 0 active — on CDNA,
// ds_bpermute returns 0 when the source lane is inactive (the R3 bug).
__global__ __launch_bounds__(256) void scan_kernel(
    const float* __restrict__ sboxes, const float* __restrict__ sscores,
    const unsigned long long* __restrict__ mat,
    const unsigned long long* __restrict__ flagw, float* __restrict__ out) {
  int b = blockIdx.x, tid = threadIdx.x;
  int lane = tid & 63, wave = tid >> 6;
  __shared__ unsigned long long mbuf[256 * NW];   // 48 KB chunk buffer
  __shared__ int list[KK];
  __shared__ unsigned long long keepLDS[NW];
  __shared__ unsigned long long flagLDS[NW];
  __shared__ int F_s;

  if (wave == 0) {
    unsigned long long fwl = (lane < NW) ? flagw[b * NW + lane] : 0ULL;
    if (lane < NW) flagLDS[lane] = fwl;
    int cnt = __popcll(fwl);
    int off = cnt;                       // inclusive prefix over 64 lanes
    for (int d = 1; d < 64; d <<= 1) {
      int o = __shfl_up(off, d);
      if (lane >= d) off += o;
    }
    int excl = off - cnt;
    unsigned long long w = fwl; int k = 0;
    while (w) {
      int r = __ffsll(w) - 1; w &= w - 1;
      list[excl + k] = lane * 64 + r; ++k;
    }
    int F = __shfl(off, 63);             // ALL lanes active for the shuffle
    if (lane == 0) F_s = F;
  }
  __syncthreads();
  int F = F_s;
  unsigned long long kw =
      (wave == 0 && lane < NW) ? ~flagLDS[lane] : 0ULL;  // unflagged -> kept

  for (int c0 = 0; c0 < F; c0 += 256) {
    int cn = min(256, F - c0);
    for (int x = tid; x < cn * NW; x += 256) {
      int q = x / NW, wd = x - q * NW;
      int i = list[c0 + q];
      mbuf[x] = (wd <= (i >> 6)) ? mat[(size_t)(b * KK + i) * NW + wd] : 0ULL;
    }
    __syncthreads();
    if (wave == 0) {
      for (int q = 0; q < cn; ++q) {
        int i = list[c0 + q];
        unsigned long long rw = (lane < NW) ? mbuf[q * NW + lane] : 0ULL;
        unsigned long long conf = __ballot((rw & kw) != 0ULL);
        if (conf == 0ULL && lane == (i >> 6)) kw |= 1ULL << (i & 63);
      }
    }
    __syncthreads();
  }
  if (wave == 0 && lane < NW) keepLDS[lane] = kw;
  __syncthreads();

  for (int e = tid; e < KK * 5; e += 256) {
    int row = e / 5, c = e - row * 5;
    bool k = (keepLDS[row >> 6] >> (row & 63)) & 1ULL;
    float v = 0.0f;
    if (k) v = (c < 4) ? sboxes[(size_t)(b * KK + row) * 4 + c]
                       : sscores[b * KK + row];
    out[(size_t)b * (KK * 5) + e] = v;
  }
}

extern "C" void kernel_launch(void* const* d_in, const int* in_sizes, int n_in,
                              void* d_out, int out_size, void* d_ws, size_t ws_size,
                              hipStream_t stream) {
  (void)in_sizes; (void)n_in; (void)out_size; (void)ws_size;
  const float* boxes   = (const float*)d_in[0];  // (M,B,N,4)
  const float* scores  = (const float*)d_in[1];  // (M,B,N)
  const int*   labels  = (const int*)d_in[2];    // (M,B,N)
  const float* weights = (const float*)d_in[3];  // (M,)
  float* out = (float*)d_out;                    // (B,K,5)

  // ws layout (bytes), total ~5.16 MB
  char* base = (char*)d_ws;
  float* sboxes  = (float*)(base + 0);                   // B*K*4 f32
  float* sscores = (float*)(base + 393216);              // B*K f32
  int*   slabels = (int*)  (base + 491520);              // B*K i32
  float* sarea   = (float*)(base + 589824);              // B*K f32
  unsigned long long* flagw = (unsigned long long*)(base + 688128); // B*NW u64
  unsigned long long* mat   = (unsigned long long*)(base + 691200); // B*K*NW u64

  rank_kernel<<<dim3(KK / 128, BB), 64, 0, stream>>>(
      boxes, scores, labels, weights, sboxes, sscores, slabels, sarea, flagw);
  tile_kernel<<<dim3(NW * (NW + 1) / 2, BB), 256, 0, stream>>>(
      sboxes, slabels, sarea, mat, flagw);
  scan_kernel<<<BB, 256, 0, stream>>>(sboxes, sscores, mat, flagw, out);
}